// Round 5
// baseline (924.076 us; speedup 1.0000x reference)
//
#include <hip/hip_runtime.h>
#include <hip/hip_bf16.h>
#include <stdint.h>

#define H       256
#define INDIM   64
#define TSTEPS  128
#define BATCH   2048
#define MROWS   8
#define OUTD    4

typedef __attribute__((ext_vector_type(8))) short bf16x8;
typedef __attribute__((ext_vector_type(4))) float f32x4;

__device__ __forceinline__ short b2s(float x) {
  __hip_bfloat16 h = __float2bfloat16(x);
  return __builtin_bit_cast(short, h);
}

// R3 swizzle (best measured). Conflict counter is dominated by the structural
// row-duplication tax (~4cy/ds_read_b128, swizzle-invariant), not bank math.
__device__ __forceinline__ int swz(int m, int n) {
  return (m * H + n) ^ ((m & 7) << 3);
}
__device__ __forceinline__ int wpk_slot(int lane) {
  return (((lane & 3) << 1) | ((lane >> 4) & 1)) |
         (((lane >> 2) & 3) << 3) | (((lane >> 5) & 1) << 5);
}

// lanes 0-31 keep a; lanes 32-63 receive b from (lane-32).
__device__ __forceinline__ float swap_hilo(float a, float b) {
#if __has_builtin(__builtin_amdgcn_permlane32_swap)
  typedef unsigned int u32x2 __attribute__((ext_vector_type(2)));
  u32x2 r = __builtin_amdgcn_permlane32_swap(
      __builtin_bit_cast(unsigned int, a),
      __builtin_bit_cast(unsigned int, b), false, false);
  return __builtin_bit_cast(float, r[0]);
#else
  float t = __shfl_xor(b, 32);
  return (threadIdx.x & 32) ? t : a;
#endif
}

#define MFMA(a, b, c) __builtin_amdgcn_mfma_f32_16x16x32_bf16((a), (b), (c), 0, 0, 0)

// 256 threads = 4 waves = 1 wave/SIMD. Each wave owns 64 N-cols (4 N-frags).
// Halves the block's ds_read_b128 count per phase vs 8 waves (the measured
// binder); MFMA issue per SIMD unchanged. Weights: 64 B-frags = 256 regs
// (AGPR half of the unified file) at 1 wave/SIMD.
__global__ __launch_bounds__(256, 1) void node_kernel(
    const float* __restrict__ g_static, const float* __restrict__ g_times,
    const float* __restrict__ g_Win, const float* __restrict__ g_bin,
    const float* __restrict__ g_W1, const float* __restrict__ g_b1,
    const float* __restrict__ g_W2, const float* __restrict__ g_b2,
    const float* __restrict__ g_Wpk, const float* __restrict__ g_bpk,
    const float* __restrict__ g_Wpd, const float* __restrict__ g_bpd,
    float* __restrict__ g_out)
{
  __shared__ __align__(16) short arg_lds[MROWS * H];
  __shared__ __align__(16) short h1_lds[MROWS * H];
  __shared__ __align__(16) short wpk_lds[8 * 64 * 8];
  __shared__ float h_lds[MROWS * H];
  __shared__ float s_lds[MROWS * INDIM];
  __shared__ float t_lds[TSTEPS];

  const int tid   = threadIdx.x;
  const int lane  = tid & 63;
  const int wid   = tid >> 6;        // 0..3; wave owns N-cols [wid*64, wid*64+64)
  const int g     = lane >> 4;       // 0..3
  const int c     = lane & 15;
  const int b0    = blockIdx.x * MROWS;
  const int ncol0 = wid * 64;
  const int am    = lane & 7;        // A-frag row (rows 8..15 duplicate 0..7)
  const int gg    = (lane >> 4) & 1;
  const int hh    = lane >> 5;
  const int cu    = ncol0 + 16 * hh + c;
  const int dm    = 4 * g;

  if (tid < TSTEPS) t_lds[tid] = g_times[tid];

  // per-lane constants
  float b1v[4], b2v[4];              // bias per N-frag (baked into accum init)
#pragma unroll
  for (int nt = 0; nt < 4; ++nt) {
    b1v[nt] = g_b1[ncol0 + nt * 16 + c];
    b2v[nt] = g_b2[ncol0 + nt * 16 + c];
  }
  const float bpkc = g_bpk[c & 3];
  const float bpdv = g_bpd[0];
  float wpd[4];
#pragma unroll
  for (int j = 0; j < 4; ++j) wpd[j] = g_Wpd[lane + 64 * j];

  // loop-invariant LDS element indices
  int ra[8], wa[2][4], ha[2][4];
#pragma unroll
  for (int kt = 0; kt < 8; ++kt) ra[kt] = swz(am, kt * 32 + g * 8);
#pragma unroll
  for (int p = 0; p < 2; ++p)
#pragma unroll
    for (int r = 0; r < 4; ++r) {
      wa[p][r] = swz(4 * gg + r, cu + 32 * p);
      ha[p][r] = (4 * gg + r) * H + cu + 32 * p;
    }

  // ---- W1,W2 -> bf16 B-fragments, 4 N-frags x 8 kt each (256 regs) ----
  bf16x8 w1f[8][4], w2f[8][4];
#pragma unroll
  for (int kt = 0; kt < 8; ++kt) {
#pragma unroll
    for (int nt = 0; nt < 4; ++nt) {
      const int n  = ncol0 + nt * 16 + c;
      const int kb = kt * 32 + g * 8;
      bf16x8 f1, f2;
#pragma unroll
      for (int u = 0; u < 8; ++u) {
        f1[u] = b2s(g_W1[(kb + u) * H + n]);
        f2[u] = b2s(g_W2[(kb + u) * H + n]);
      }
      w1f[kt][nt] = f1;
      w2f[kt][nt] = f2;
    }
  }

  // ---- Wpk B-fragments -> LDS (wave 0) ----
  if (wid == 0) {
    const int slot = wpk_slot(lane);
#pragma unroll
    for (int kt = 0; kt < 8; ++kt) {
      bf16x8 f;
#pragma unroll
      for (int u = 0; u < 8; ++u) {
        const int k = kt * 32 + g * 8 + u;
        f[u] = (c < OUTD) ? b2s(g_Wpk[k * OUTD + c]) : (short)0;
      }
      *(bf16x8*)(wpk_lds + kt * 512 + slot * 8) = f;
    }
  }

  // ---- h0 = static @ W_in + b_in ----
  s_lds[tid]       = g_static[(b0 + (tid >> 6)) * INDIM + (tid & 63)];
  s_lds[tid + 256] = g_static[(b0 + ((tid + 256) >> 6)) * INDIM + (tid & 63)];
  __syncthreads();
  {
    const int m  = tid >> 5;           // 8 rows, 32 threads/row
    const int n0 = (tid & 31) * 8;     // 8 cols/thread
    float a[8];
#pragma unroll
    for (int j = 0; j < 8; ++j) a[j] = g_bin[n0 + j];
#pragma unroll 4
    for (int k = 0; k < INDIM; ++k) {
      const float sv = s_lds[m * INDIM + k];
      const f32x4 w0 = *(const f32x4*)(g_Win + k * H + n0);
      const f32x4 w1 = *(const f32x4*)(g_Win + k * H + n0 + 4);
#pragma unroll
      for (int j = 0; j < 4; ++j) {
        a[j]     += sv * w0[j];
        a[j + 4] += sv * w1[j];
      }
    }
#pragma unroll
    for (int j = 0; j < 8; ++j) {
      h_lds[m * H + n0 + j]     = a[j];
      arg_lds[swz(m, n0 + j)]   = b2s(a[j]);
    }
  }
  __syncthreads();

  float hb[2][4];
#pragma unroll
  for (int p = 0; p < 2; ++p)
#pragma unroll
    for (int r = 0; r < 4; ++r) hb[p][r] = h_lds[ha[p][r]];

  const int wslot = wpk_slot(lane);
  auto emit_pk = [&](int t) {
    if (wid == 0) {
      f32x4 acc = {0.f, 0.f, 0.f, 0.f};
#pragma unroll
      for (int kt = 0; kt < 8; ++kt) {
        const bf16x8 aA = *(const bf16x8*)(arg_lds + ra[kt]);
        const bf16x8 bW = *(const bf16x8*)(wpk_lds + kt * 512 + wslot * 8);
        acc = MFMA(aA, bW, acc);
      }
      if (g < 2 && c < OUTD) {
#pragma unroll
        for (int r = 0; r < 4; ++r)
          g_out[((size_t)(b0 + dm + r) * TSTEPS + t) * OUTD + c] = acc[r] + bpkc;
      }
    }
  };

  emit_pk(0);

  const f32x4 vz = {0.f, 0.f, 0.f, 0.f};
  for (int t = 1; t < TSTEPS; ++t) {
    const float dt = t_lds[t] - t_lds[t - 1];
    const float s6 = dt * (1.0f / 6.0f);
    float ks[2][4];

#pragma unroll
    for (int ev = 0; ev < 4; ++ev) {
      // ---- phase 1: h1 = tanh(arg @ W1 + b1) ----
      {
        f32x4 cA[4], cB[4];
#pragma unroll
        for (int nt = 0; nt < 4; ++nt) {
          cA[nt] = f32x4{b1v[nt], b1v[nt], b1v[nt], b1v[nt]};
          cB[nt] = vz;
        }
#pragma unroll
        for (int kt = 0; kt < 4; ++kt) {
          const bf16x8 fA = *(const bf16x8*)(arg_lds + ra[kt]);
          const bf16x8 fB = *(const bf16x8*)(arg_lds + ra[kt + 4]);
#pragma unroll
          for (int nt = 0; nt < 4; ++nt) {
            cA[nt] = MFMA(fA, w1f[kt][nt], cA[nt]);
            cB[nt] = MFMA(fB, w1f[kt + 4][nt], cB[nt]);
          }
        }
        f32x4 S[4];
#pragma unroll
        for (int nt = 0; nt < 4; ++nt) S[nt] = cA[nt] + cB[nt];
#pragma unroll
        for (int p = 0; p < 2; ++p)
#pragma unroll
          for (int r = 0; r < 4; ++r) {
            const float v = swap_hilo(S[2 * p][r], S[2 * p + 1][r]);
            const float e = __expf(2.0f * v);
            const float th = 1.0f - __fdividef(2.0f, e + 1.0f);
            h1_lds[wa[p][r]] = b2s(th);
          }
      }
      __syncthreads();

      // ---- phase 2: k = h1 @ W2 + b2, RK4 update ----
      {
        f32x4 cA[4], cB[4];
#pragma unroll
        for (int nt = 0; nt < 4; ++nt) {
          cA[nt] = f32x4{b2v[nt], b2v[nt], b2v[nt], b2v[nt]};
          cB[nt] = vz;
        }
#pragma unroll
        for (int kt = 0; kt < 4; ++kt) {
          const bf16x8 fA = *(const bf16x8*)(h1_lds + ra[kt]);
          const bf16x8 fB = *(const bf16x8*)(h1_lds + ra[kt + 4]);
#pragma unroll
          for (int nt = 0; nt < 4; ++nt) {
            cA[nt] = MFMA(fA, w2f[kt][nt], cA[nt]);
            cB[nt] = MFMA(fB, w2f[kt + 4][nt], cB[nt]);
          }
        }
        f32x4 S[4];
#pragma unroll
        for (int nt = 0; nt < 4; ++nt) S[nt] = cA[nt] + cB[nt];
#pragma unroll
        for (int p = 0; p < 2; ++p)
#pragma unroll
          for (int r = 0; r < 4; ++r) {
            const float kv = swap_hilo(S[2 * p][r], S[2 * p + 1][r]);
            if (ev == 0)      ks[p][r] = kv;
            else if (ev == 3) ks[p][r] += kv;
            else              ks[p][r] += 2.0f * kv;
            if (ev < 3) {
              const float cc = (ev == 2) ? dt : 0.5f * dt;
              arg_lds[wa[p][r]] = b2s(__builtin_fmaf(cc, kv, hb[p][r]));
            } else {
              hb[p][r] = __builtin_fmaf(s6, ks[p][r], hb[p][r]);
              arg_lds[wa[p][r]] = b2s(hb[p][r]);
            }
          }
      }
      __syncthreads();
    }
    emit_pk(t);
  }

  // ---- pd = h_T @ W_pd + b_pd ----
#pragma unroll
  for (int p = 0; p < 2; ++p)
#pragma unroll
    for (int r = 0; r < 4; ++r) h_lds[ha[p][r]] = hb[p][r];
  __syncthreads();
#pragma unroll
  for (int rr = 0; rr < 2; ++rr) {
    const int row = wid + 4 * rr;
    float p = 0.0f;
#pragma unroll
    for (int j = 0; j < 4; ++j) p += h_lds[row * H + lane + 64 * j] * wpd[j];
#pragma unroll
    for (int m = 1; m < 64; m <<= 1) p += __shfl_xor(p, m);
    if (lane == 0) g_out[(size_t)BATCH * TSTEPS * OUTD + b0 + row] = p + bpdv;
  }
}

extern "C" void kernel_launch(void* const* d_in, const int* in_sizes, int n_in,
                              void* d_out, int out_size, void* d_ws, size_t ws_size,
                              hipStream_t stream) {
  const float* g_static = (const float*)d_in[0];
  const float* g_times  = (const float*)d_in[1];
  const float* g_Win    = (const float*)d_in[2];
  const float* g_bin    = (const float*)d_in[3];
  const float* g_W1     = (const float*)d_in[4];
  const float* g_b1     = (const float*)d_in[5];
  const float* g_W2     = (const float*)d_in[6];
  const float* g_b2     = (const float*)d_in[7];
  const float* g_Wpk    = (const float*)d_in[8];
  const float* g_bpk    = (const float*)d_in[9];
  const float* g_Wpd    = (const float*)d_in[10];
  const float* g_bpd    = (const float*)d_in[11];

  node_kernel<<<dim3(BATCH / MROWS), dim3(256), 0, stream>>>(
      g_static, g_times, g_Win, g_bin, g_W1, g_b1, g_W2, g_b2,
      g_Wpk, g_bpk, g_Wpd, g_bpd, (float*)d_out);
}

// Round 7
// 686.884 us; speedup vs baseline: 1.3453x; 1.3453x over previous
//
#include <hip/hip_runtime.h>
#include <hip/hip_bf16.h>
#include <stdint.h>

#define H       256
#define INDIM   64
#define TSTEPS  128
#define BATCH   2048
#define MROWS   8
#define OUTD    4

typedef __attribute__((ext_vector_type(8))) short bf16x8;
typedef __attribute__((ext_vector_type(4))) float f32x4;

__device__ __forceinline__ short b2s(float x) {
  __hip_bfloat16 h = __float2bfloat16(x);
  return __builtin_bit_cast(short, h);
}

// [16][256] bf16 tile; rows 8-15 are physical COPIES of rows 0-7 so that
// no two lanes of an A-frag ds_read_b128 share an address (the measured
// 4.07cy/read tax was same-addr-pair-invariant under swizzle changes).
// Granule mix smix(m) = (m&7)^(m>>3): 16 rows -> 8 granule slots hit
// exactly 2x by DISTINCT addresses (2-way distinct = ~free, m136).
__device__ __forceinline__ int sidx16(int m, int n) {
  const int smix = ((m & 7) ^ (m >> 3)) & 7;
  return m * H + (n ^ (smix << 3));
}
__device__ __forceinline__ int wpk_slot(int lane) {
  return (((lane & 3) << 1) | ((lane >> 4) & 1)) |
         (((lane >> 2) & 3) << 3) | (((lane >> 5) & 1) << 5);
}

// lanes 0-31 keep a; lanes 32-63 receive b from (lane-32).
__device__ __forceinline__ float swap_hilo(float a, float b) {
#if __has_builtin(__builtin_amdgcn_permlane32_swap)
  typedef unsigned int u32x2 __attribute__((ext_vector_type(2)));
  u32x2 r = __builtin_amdgcn_permlane32_swap(
      __builtin_bit_cast(unsigned int, a),
      __builtin_bit_cast(unsigned int, b), false, false);
  return __builtin_bit_cast(float, r[0]);
#else
  float t = __shfl_xor(b, 32);
  return (threadIdx.x & 32) ? t : a;
#endif
}

#define MFMA(a, b, c) __builtin_amdgcn_mfma_f32_16x16x32_bf16((a), (b), (c), 0, 0, 0)

__global__ __launch_bounds__(512, 1) void node_kernel(
    const float* __restrict__ g_static, const float* __restrict__ g_times,
    const float* __restrict__ g_Win, const float* __restrict__ g_bin,
    const float* __restrict__ g_W1, const float* __restrict__ g_b1,
    const float* __restrict__ g_W2, const float* __restrict__ g_b2,
    const float* __restrict__ g_Wpk, const float* __restrict__ g_bpk,
    const float* __restrict__ g_Wpd, const float* __restrict__ g_bpd,
    float* __restrict__ g_out)
{
  __shared__ __align__(16) short arg_lds[16 * H];   // 16 rows (8 real + 8 copy)
  __shared__ __align__(16) short h1_lds[16 * H];
  __shared__ __align__(16) short wpk_lds[8 * 64 * 8];
  __shared__ float h_lds[MROWS * H];
  __shared__ float s_lds[MROWS * INDIM];
  __shared__ float t_lds[TSTEPS];

  const int tid   = threadIdx.x;
  const int lane  = tid & 63;
  const int wid   = tid >> 6;        // 8 waves; wave owns N-cols [wid*32, wid*32+32)
  const int g     = lane >> 4;       // 0..3
  const int c     = lane & 15;
  const int b0    = blockIdx.x * MROWS;
  const int ncol0 = wid * 32;
  const int am    = lane & 15;       // A-frag row in the 16-row (dup-copy) tile
  const int gg    = (lane >> 4) & 1;
  const int hh    = lane >> 5;
  const int colu  = ncol0 + 16 * hh + c;
  const int dm    = 4 * g;

  if (tid < TSTEPS) t_lds[tid] = g_times[tid];

  const float b1u2 = 2.0f * g_b1[colu];
  const float b2u  = g_b2[colu];
  const float bpkc = g_bpk[c & 3];
  const float bpdv = g_bpd[0];
  float wpd[4];
#pragma unroll
  for (int j = 0; j < 4; ++j) wpd[j] = g_Wpd[lane + 64 * j];

  // ---- loop-invariant swizzled LDS element indices ----
  // Parity stagger: odd waves take kt 4..7 in chain A, 0..3 in chain B —
  // spreads the post-barrier LDS read burst across the two wave cohorts.
  const int ko = (wid & 1) ? 4 : 0;
  int ra[8];                 // ra[i]: i<4 -> chain A (kt=ko+i), i>=4 -> chain B
#pragma unroll
  for (int i = 0; i < 4; ++i) {
    ra[i]     = sidx16(am, (ko + i) * 32 + g * 8);
    ra[i + 4] = sidx16(am, ((ko ^ 4) + i) * 32 + g * 8);
  }
  int wlo[4], whi[4], ha[4];
#pragma unroll
  for (int r = 0; r < 4; ++r) {
    wlo[r] = sidx16(4 * gg + r, colu);
    whi[r] = sidx16(4 * gg + r + 8, colu);
    ha[r]  = (4 * gg + r) * H + colu;
  }

  // ---- W1,W2 -> bf16 B-fragments in registers (order matches ra) ----
  bf16x8 w1f[8][2], w2f[8][2];
#pragma unroll
  for (int i = 0; i < 8; ++i) {
    const int kt = (i < 4) ? (ko + i) : ((ko ^ 4) + i - 4);
#pragma unroll
    for (int nt = 0; nt < 2; ++nt) {
      const int n  = ncol0 + nt * 16 + c;
      const int kb = kt * 32 + g * 8;
      bf16x8 f1, f2;
#pragma unroll
      for (int u = 0; u < 8; ++u) {
        f1[u] = b2s(g_W1[(kb + u) * H + n]);
        f2[u] = b2s(g_W2[(kb + u) * H + n]);
      }
      w1f[i][nt] = f1;
      w2f[i][nt] = f2;
    }
  }

  // ---- Wpk B-fragments -> LDS (wave 0); emit_pk uses ra order of wave 0 (ko=0) ----
  if (wid == 0) {
    const int slot = wpk_slot(lane);
#pragma unroll
    for (int kt = 0; kt < 8; ++kt) {
      bf16x8 f;
#pragma unroll
      for (int u = 0; u < 8; ++u) {
        const int k = kt * 32 + g * 8 + u;
        f[u] = (c < OUTD) ? b2s(g_Wpk[k * OUTD + c]) : (short)0;
      }
      *(bf16x8*)(wpk_lds + kt * 512 + slot * 8) = f;
    }
  }

  // ---- h0 = static @ W_in + b_in ----
  s_lds[tid] = g_static[(b0 + (tid >> 6)) * INDIM + (tid & 63)];
  __syncthreads();
  {
    const int m  = tid >> 6;
    const int n0 = (tid & 63) * 4;
    float a0 = g_bin[n0], a1 = g_bin[n0 + 1], a2 = g_bin[n0 + 2], a3 = g_bin[n0 + 3];
#pragma unroll 8
    for (int k = 0; k < INDIM; ++k) {
      const float sv = s_lds[m * INDIM + k];
      const f32x4 w = *(const f32x4*)(g_Win + k * H + n0);
      a0 += sv * w[0]; a1 += sv * w[1]; a2 += sv * w[2]; a3 += sv * w[3];
    }
    h_lds[m * H + n0] = a0;     h_lds[m * H + n0 + 1] = a1;
    h_lds[m * H + n0 + 2] = a2; h_lds[m * H + n0 + 3] = a3;
    const float av[4] = {a0, a1, a2, a3};
#pragma unroll
    for (int j = 0; j < 4; ++j) {
      arg_lds[sidx16(m, n0 + j)]     = b2s(av[j]);
      arg_lds[sidx16(m + 8, n0 + j)] = b2s(av[j]);
    }
  }
  __syncthreads();

  float hb[4];
#pragma unroll
  for (int r = 0; r < 4; ++r) hb[r] = h_lds[ha[r]];

  const int wslot = wpk_slot(lane);
  auto emit_pk = [&](int t) {
    if (wid == 0) {
      f32x4 acc = {0.f, 0.f, 0.f, 0.f};
#pragma unroll
      for (int kt = 0; kt < 8; ++kt) {   // wave 0: ra[i] covers kt=i
        const bf16x8 aA = *(const bf16x8*)(arg_lds + ra[kt]);
        const bf16x8 bW = *(const bf16x8*)(wpk_lds + kt * 512 + wslot * 8);
        acc = MFMA(aA, bW, acc);
      }
      if (g < 2 && c < OUTD) {
#pragma unroll
        for (int r = 0; r < 4; ++r)
          g_out[((size_t)(b0 + dm + r) * TSTEPS + t) * OUTD + c] = acc[r] + bpkc;
      }
    }
  };

  emit_pk(0);

  const f32x4 vz = {0.f, 0.f, 0.f, 0.f};
  for (int t = 1; t < TSTEPS; ++t) {
    const float dt = t_lds[t] - t_lds[t - 1];
    const float s6 = dt * (1.0f / 6.0f);
    float ks[4];

#pragma unroll
    for (int ev = 0; ev < 4; ++ev) {
      // ---- phase 1: h1 = tanh(arg @ W1 + b1) ----
      {
        f32x4 A0 = vz, A1 = vz, B0 = vz, B1 = vz;
#pragma unroll
        for (int i = 0; i < 4; ++i) {
          const bf16x8 fA = *(const bf16x8*)(arg_lds + ra[i]);
          const bf16x8 fB = *(const bf16x8*)(arg_lds + ra[i + 4]);
          A0 = MFMA(fA, w1f[i][0], A0);
          A1 = MFMA(fA, w1f[i][1], A1);
          B0 = MFMA(fB, w1f[i + 4][0], B0);
          B1 = MFMA(fB, w1f[i + 4][1], B1);
        }
        const f32x4 S0 = A0 + B0;
        const f32x4 S1 = A1 + B1;
#pragma unroll
        for (int r = 0; r < 4; ++r) {
          const float v  = swap_hilo(S0[r], S1[r]);
          const float e  = __expf(__builtin_fmaf(2.0f, v, b1u2));
          const float th = 1.0f - __fdividef(2.0f, e + 1.0f);
          const short sv = b2s(th);
          h1_lds[wlo[r]] = sv;
          h1_lds[whi[r]] = sv;
        }
      }
      __syncthreads();

      // ---- phase 2: k = h1 @ W2 + b2, RK4 update ----
      {
        f32x4 A0 = vz, A1 = vz, B0 = vz, B1 = vz;
#pragma unroll
        for (int i = 0; i < 4; ++i) {
          const bf16x8 fA = *(const bf16x8*)(h1_lds + ra[i]);
          const bf16x8 fB = *(const bf16x8*)(h1_lds + ra[i + 4]);
          A0 = MFMA(fA, w2f[i][0], A0);
          A1 = MFMA(fA, w2f[i][1], A1);
          B0 = MFMA(fB, w2f[i + 4][0], B0);
          B1 = MFMA(fB, w2f[i + 4][1], B1);
        }
        const f32x4 S0 = A0 + B0;
        const f32x4 S1 = A1 + B1;
#pragma unroll
        for (int r = 0; r < 4; ++r) {
          const float kv = swap_hilo(S0[r], S1[r]) + b2u;
          if (ev == 0)      ks[r] = kv;
          else if (ev == 3) ks[r] += kv;
          else              ks[r] += 2.0f * kv;
          short sv;
          if (ev < 3) {
            const float cc = (ev == 2) ? dt : 0.5f * dt;
            sv = b2s(__builtin_fmaf(cc, kv, hb[r]));
          } else {
            hb[r] = __builtin_fmaf(s6, ks[r], hb[r]);
            sv = b2s(hb[r]);
          }
          arg_lds[wlo[r]] = sv;
          arg_lds[whi[r]] = sv;
        }
      }
      __syncthreads();
    }
    emit_pk(t);
  }

  // ---- pd = h_T @ W_pd + b_pd ----
#pragma unroll
  for (int r = 0; r < 4; ++r) h_lds[ha[r]] = hb[r];
  __syncthreads();
  {
    float p = 0.0f;
#pragma unroll
    for (int j = 0; j < 4; ++j) p += h_lds[wid * H + lane + 64 * j] * wpd[j];
#pragma unroll
    for (int m = 1; m < 64; m <<= 1) p += __shfl_xor(p, m);
    if (lane == 0) g_out[(size_t)BATCH * TSTEPS * OUTD + b0 + wid] = p + bpdv;
  }
}

extern "C" void kernel_launch(void* const* d_in, const int* in_sizes, int n_in,
                              void* d_out, int out_size, void* d_ws, size_t ws_size,
                              hipStream_t stream) {
  const float* g_static = (const float*)d_in[0];
  const float* g_times  = (const float*)d_in[1];
  const float* g_Win    = (const float*)d_in[2];
  const float* g_bin    = (const float*)d_in[3];
  const float* g_W1     = (const float*)d_in[4];
  const float* g_b1     = (const float*)d_in[5];
  const float* g_W2     = (const float*)d_in[6];
  const float* g_b2     = (const float*)d_in[7];
  const float* g_Wpk    = (const float*)d_in[8];
  const float* g_bpk    = (const float*)d_in[9];
  const float* g_Wpd    = (const float*)d_in[10];
  const float* g_bpd    = (const float*)d_in[11];

  node_kernel<<<dim3(BATCH / MROWS), dim3(512), 0, stream>>>(
      g_static, g_times, g_Win, g_bin, g_W1, g_b1, g_W2, g_b2,
      g_Wpk, g_bpk, g_Wpd, g_bpd, (float*)d_out);
}